// Round 3
// baseline (83522.968 us; speedup 1.0000x reference)
//
#include <hip/hip_runtime.h>
#include <hip/hip_cooperative_groups.h>
#include <math.h>

namespace cg = cooperative_groups;

// ---------- helpers ----------
__device__ __forceinline__ float4 ld4(const float* p) { return *reinterpret_cast<const float4*>(p); }
__device__ __forceinline__ float dot4(float4 a, float4 b) { return a.x*b.x + a.y*b.y + a.z*b.z + a.w*b.w; }
__device__ __forceinline__ float sigm(float x) { return 1.f/(1.f+expf(-x)); }
__device__ __forceinline__ float gumb(float u) {
  u = fminf(fmaxf(u, 1e-6f), 1.f - 1e-6f);
  return -logf(-logf(u));
}

// ---------- repack conv weights: [o][i][k] -> [o][k*512+i]; pb_fW too; codebook row sumsq ----------
__launch_bounds__(256)
__global__ void repack_k(const float* __restrict__ convW, const float* __restrict__ fW,
                         const float* __restrict__ cbk,
                         float* __restrict__ W0R, float* __restrict__ W1R,
                         float* __restrict__ WFR, float* __restrict__ CBSQ)
{
  long i = (long)blockIdx.x*256 + threadIdx.x;
  const long NC = 2L*512*2560;
  if (i < NC) {
    int l = (int)(i / (512*2560)); int rem = (int)(i % (512*2560));
    int n = rem / 2560; int r2 = rem - n*2560; int k = r2 >> 9; int ii = r2 & 511;
    float v = convW[(((size_t)(l*512 + n)*512 + ii)*5) + k];
    (l ? W1R : W0R)[(size_t)n*2560 + r2] = v;
  } else if (i < NC + 2*2560) {
    long j = i - NC; int o = (int)(j / 2560); int r2 = (int)(j - o*2560);
    int k = r2 >> 9; int ii = r2 & 511;
    WFR[(size_t)o*2560 + r2] = fW[((size_t)o*512 + ii)*5 + k];
  } else if (i < NC + 2*2560 + 10) {
    int j = (int)(i - (NC + 2*2560));
    float s = 0.f;
    for (int d = 0; d < 512; ++d) { float c = cbk[j*512 + d]; s += c*c; }
    CBSQ[j] = s;
  }
}

// ---------- tiled f32 GEMM: C[M,N] = A[M,K] @ Bw[N,K]^T (+bias) ----------
// MODE 0 plain, 1 comb-gather, 2 conv-im2col, 3 relu, 4 dec-row-remap
template<int MODE>
__launch_bounds__(256)
__global__ void gemm_k(const float* __restrict__ A, const float* __restrict__ Bw,
                       const float* __restrict__ bias, float* __restrict__ C,
                       int M, int N, int K, int ldc,
                       const int* __restrict__ aux_i, const float* __restrict__ aux_f)
{
  __shared__ float As[16][132];
  __shared__ float Bs[16][132];
  const int tid = threadIdx.x;
  const int ty = tid >> 4, tx = tid & 15;
  const int m0 = blockIdx.x * 128, n0 = blockIdx.y * 128;
  float acc[8][8];
#pragma unroll
  for (int i = 0; i < 8; ++i)
#pragma unroll
    for (int j = 0; j < 8; ++j) acc[i][j] = 0.f;

  for (int k0 = 0; k0 < K; k0 += 16) {
#pragma unroll
    for (int jj = 0; jj < 2; ++jj) {
      int li = tid + jj*256;
      int row = li >> 2;
      int kc = (li & 3) << 2;
      int gm = m0 + row, gk = k0 + kc;
      float4 av;
      if constexpr (MODE == 2) {
        int b = gm >> 7, s = gm & 127;
        int kk = gk >> 9, ii = gk & 511;
        int sr = s + kk - 4;
        if (sr >= 0) av = ld4(A + (((size_t)((b<<7)+sr))<<9) + ii);
        else av = make_float4(0.f,0.f,0.f,0.f);
      } else if constexpr (MODE == 1) {
        if (gk < 64) av = ld4(aux_f + (size_t)aux_i[gm]*64 + gk);
        else av = ld4(A + (size_t)gm*256 + (gk - 64));
      } else {
        av = ld4(A + (size_t)gm*K + gk);
      }
      As[kc+0][row] = av.x; As[kc+1][row] = av.y; As[kc+2][row] = av.z; As[kc+3][row] = av.w;
      float4 bv = ld4(Bw + (size_t)(n0+row)*K + gk);
      Bs[kc+0][row] = bv.x; Bs[kc+1][row] = bv.y; Bs[kc+2][row] = bv.z; Bs[kc+3][row] = bv.w;
    }
    __syncthreads();
#pragma unroll
    for (int kk = 0; kk < 16; ++kk) {
      float a[8], b[8];
      *(float4*)&a[0] = *(const float4*)&As[kk][ty*4];
      *(float4*)&a[4] = *(const float4*)&As[kk][ty*4 + 64];
      *(float4*)&b[0] = *(const float4*)&Bs[kk][tx*4];
      *(float4*)&b[4] = *(const float4*)&Bs[kk][tx*4 + 64];
#pragma unroll
      for (int i = 0; i < 8; ++i)
#pragma unroll
        for (int j = 0; j < 8; ++j) acc[i][j] += a[i]*b[j];
    }
    __syncthreads();
  }
#pragma unroll
  for (int i = 0; i < 8; ++i) {
    int m = m0 + ty*4 + (i & 3) + ((i >> 2) << 6);
    int crow = m;
    if constexpr (MODE == 4) crow = ((m & 63) << 7) + (m >> 6);
#pragma unroll
    for (int jh = 0; jh < 2; ++jh) {
      int n = n0 + tx*4 + jh*64;
      float4 v;
      float* vp = &v.x;
#pragma unroll
      for (int q = 0; q < 4; ++q) {
        float t = acc[i][jh*4 + q];
        if (bias) t += bias[n + q];
        if constexpr (MODE == 3) t = fmaxf(t, 0.f);
        vp[q] = t;
      }
      *(float4*)(C + (size_t)crow*ldc + n) = v;
    }
  }
}

// ---------- per-channel stats over (b,s) ----------
__launch_bounds__(256)
__global__ void stats_k(const float* __restrict__ y, double* __restrict__ st)
{
  const int blk = blockIdx.x;   // 64 blocks x 128 rows
  const int o = threadIdx.x;    // channel o and o+256
  double s0 = 0, q0 = 0, s1 = 0, q1 = 0;
  for (int r = 0; r < 128; ++r) {
    const float* row = y + ((size_t)(blk*128 + r))*512;
    float v0 = row[o], v1 = row[o + 256];
    s0 += v0; q0 += (double)v0*(double)v0;
    s1 += v1; q1 += (double)v1*(double)v1;
  }
  atomicAdd(&st[o], s0);        atomicAdd(&st[512 + o], q0);
  atomicAdd(&st[o + 256], s1);  atomicAdd(&st[512 + o + 256], q1);
}

__launch_bounds__(256)
__global__ void statsfin_k(const double* __restrict__ st, float* __restrict__ mv)
{
  int o = blockIdx.x*256 + threadIdx.x;
  if (o >= 512) return;
  double mean = st[o] / 8192.0;
  double var = st[512 + o] / 8192.0 - mean*mean;
  mv[o] = (float)mean;
  mv[512 + o] = (float)(1.0 / sqrt(var + 1e-5));
}

__launch_bounds__(256)
__global__ void normelu_k(const float* __restrict__ y, const float* __restrict__ mv,
                          const float* __restrict__ gamma, const float* __restrict__ beta,
                          float* __restrict__ x)
{
  int e4 = blockIdx.x*256 + threadIdx.x;
  if (e4 >= 8192*128) return;
  int o = (e4 & 127) << 2;
  float4 v = ld4(y + (size_t)e4*4);
  float* vp = &v.x;
  float r[4];
#pragma unroll
  for (int q = 0; q < 4; ++q) {
    float t = (vp[q] - mv[o+q]) * mv[512+o+q] * gamma[o+q] + beta[o+q];
    r[q] = t > 0.f ? t : expm1f(t);
  }
  *(float4*)(x + (size_t)e4*4) = make_float4(r[0], r[1], r[2], r[3]);
}

// ---------- final conv (D->2) + gumbel hard argmax -> read bit ----------
__launch_bounds__(64)
__global__ void fconv_k(const float* __restrict__ x, const float* __restrict__ WFR,
                        const float* __restrict__ fb, const float* __restrict__ bnd_u,
                        float* __restrict__ read)
{
  const int m = blockIdx.x;      // (b,s)
  const int l = threadIdx.x;
  const int b = m >> 7, s = m & 127;
  float a0 = 0.f, a1 = 0.f;
  for (int k = 0; k < 5; ++k) {
    int sr = s + k - 4;
    if (sr < 0) continue;
    const float* xr = x + ((size_t)((b<<7)+sr))*512;
    const float* w0 = WFR + k*512;
    const float* w1 = WFR + 2560 + k*512;
#pragma unroll
    for (int it = 0; it < 8; ++it) { float xv = xr[it*64 + l]; a0 += xv*w0[it*64 + l]; a1 += xv*w1[it*64 + l]; }
  }
  for (int off = 32; off; off >>= 1) { a0 += __shfl_down(a0, off); a1 += __shfl_down(a1, off); }
  if (l == 0) {
    a0 += fb[0]; a1 += fb[1];
    float g0 = gumb(bnd_u[(size_t)m*2 + 0]);
    float g1 = gumb(bnd_u[(size_t)m*2 + 1]);
    read[(s<<6) + b] = (a0 + g0 >= a1 + g1) ? 1.f : 0.f;  // argmax==0 -> read=1
  }
}

// ---------- cooperative sweep kernel: 3 GRUs x 128 steps, gi folded in ----------
// 256 blocks x 768 threads; block owns 6 linear (sweep,d) pairs; k-split x2 per pair.
struct SweepArgs {
  const float* feat; const float* read;
  const float* Wi; const float* Wh; const float* bi; const float* bh;
  float* azin; float* opf; float* hst;
};

__launch_bounds__(768)
__global__ void sweep_k(SweepArgs a)
{
  cg::grid_group grid = cg::this_grid();
  const int kh = threadIdx.x & 1;
  const int u  = threadIdx.x >> 1;      // 0..383
  const int j  = u % 6;
  const int b  = u / 6;                 // 0..63
  const int pair = blockIdx.x*6 + j;    // 0..1535
  const int sweep = pair >> 9;          // 0..2
  const int d = pair & 511;
  const size_t kho = (size_t)kh*64;     // float4 offset (half of 128)
  const float* Wis = a.Wi + (size_t)sweep*1536*512;
  const float* Whs = a.Wh + (size_t)sweep*1536*512;
  const float4* wir = (const float4*)(Wis + (size_t)d*512) + kho;
  const float4* wiz = (const float4*)(Wis + (size_t)(512+d)*512) + kho;
  const float4* win = (const float4*)(Wis + (size_t)(1024+d)*512) + kho;
  const float4* whr = (const float4*)(Whs + (size_t)d*512) + kho;
  const float4* whz = (const float4*)(Whs + (size_t)(512+d)*512) + kho;
  const float4* whn = (const float4*)(Whs + (size_t)(1024+d)*512) + kho;
  const float bir = a.bi[sweep*1536 + d], biz = a.bi[sweep*1536 + 512 + d], bin = a.bi[sweep*1536 + 1024 + d];
  const float bhr = a.bh[sweep*1536 + d], bhz = a.bh[sweep*1536 + 512 + d], bhn = a.bh[sweep*1536 + 1024 + d];
  float* hbase = a.hst + (size_t)sweep*2*64*512;
  for (int t = 0; t < 128; ++t) {
    const int src = (sweep == 1) ? (127 - t) : t;
    const float4* fx = (const float4*)(a.feat + ((size_t)((b<<7)+src))*512) + kho;
    const float* hrowp = hbase + ((size_t)((t&1)*64 + b))*512;
    const float4* hx = (const float4*)hrowp + kho;
    float ir = 0.f, iz = 0.f, in_ = 0.f, hr = 0.f, hz = 0.f, hn = 0.f;
#pragma unroll 4
    for (int k = 0; k < 64; ++k) {
      float4 f = fx[k], h = hx[k];
      ir += dot4(f, wir[k]); iz += dot4(f, wiz[k]); in_ += dot4(f, win[k]);
      hr += dot4(h, whr[k]); hz += dot4(h, whz[k]); hn += dot4(h, whn[k]);
    }
    ir += __shfl_xor(ir, 1); iz += __shfl_xor(iz, 1); in_ += __shfl_xor(in_, 1);
    hr += __shfl_xor(hr, 1); hz += __shfl_xor(hz, 1); hn += __shfl_xor(hn, 1);
    float rg = sigm(ir + bir + hr + bhr);
    float zg = sigm(iz + biz + hz + bhz);
    float ng = tanhf(in_ + bin + rg*(hn + bhn));
    float hp = hrowp[d];
    float hnew = (1.f - zg)*ng + zg*hp;
    float rd = a.read[(src<<6) + b];
    if (kh == 0) {
      if (sweep == 0)      a.azin[((size_t)((src<<6)+b))*1024 + d] = hnew;
      else if (sweep == 1) a.azin[((size_t)((src<<6)+b))*1024 + 512 + d] = hnew;
      else                 a.opf [((size_t)((src<<6)+b))*512 + d] = hnew;
      hbase[((size_t)(((t+1)&1)*64 + b))*512 + d] = hnew*(1.f - rd);
    }
    __threadfence();
    grid.sync();
  }
}

// ---------- VQ distance / idx / partial loss ----------
__launch_bounds__(64)
__global__ void dist_k(const float* __restrict__ zf, const float* __restrict__ cbk,
                       const float* __restrict__ cbsq, const float* __restrict__ vq_u,
                       const float* __restrict__ read, int* __restrict__ idx,
                       float* __restrict__ part)
{
  const int m = blockIdx.x;     // (s,b)
  const int l = threadIdx.x;
  const float* z = zf + (size_t)m*512;
  float acc[10];
#pragma unroll
  for (int j = 0; j < 10; ++j) acc[j] = 0.f;
  float sq = 0.f;
  for (int it = 0; it < 8; ++it) {
    float zv = z[it*64 + l];
    sq += zv*zv;
#pragma unroll
    for (int j = 0; j < 10; ++j) acc[j] += zv * cbk[j*512 + it*64 + l];
  }
  for (int off = 32; off; off >>= 1) {
    sq += __shfl_down(sq, off);
#pragma unroll
    for (int j = 0; j < 10; ++j) acc[j] += __shfl_down(acc[j], off);
  }
  int bj = 0;
  if (l == 0) {
    const int s = m >> 6, b = m & 63;
    float sd[10]; float mx = -1e30f;
#pragma unroll
    for (int j = 0; j < 10; ++j) { float dist = sq + cbsq[j] - 2.f*acc[j]; sd[j] = -dist/0.1f; mx = fmaxf(mx, sd[j]); }
    float best = -1e30f;
#pragma unroll
    for (int j = 0; j < 10; ++j) {
      float v = fminf(fmaxf(sd[j] - mx, -1000.f), 10.f);
      v += gumb(vq_u[((size_t)((b<<7)+s))*10 + j]);
      if (v > best) { best = v; bj = j; }
    }
    idx[m] = bj;
  }
  bj = __shfl(bj, 0);
  float e2 = 0.f;
  for (int it = 0; it < 8; ++it) { float dv = cbk[bj*512 + it*64 + l] - z[it*64 + l]; e2 += dv*dv; }
  for (int off = 32; off; off >>= 1) e2 += __shfl_down(e2, off);
  if (l == 0) part[m] = read[m]*e2;
}

// ---------- cooperative main scan: 4-deep pipelined, 1 sync/phase ----------
struct ScanArgs {
  const float* zf; const float* cbk; const int* idx; const float* read;
  const float* opf; const float* eps;
  const float* Wi3; const float* Wh3; const float* bi3; const float* bh3;
  const float* ubWi; const float* ubWh; const float* ubbi; const float* ubbh;
  const float* pomW; const float* pomb; const float* posW; const float* posb;
  const float* afW; const float* afb; const float* ofW; const float* ofb;
  float* AZ; float* AB; float* OB; float* OZ; float* AF; float* ofs;
};

__device__ __forceinline__ void scan_stageA(const ScanArgs& a, int t, int vt, int stride)
{
  const int rp = t & 1, wp = rp ^ 1;
  for (int o = vt; o < 64*512; o += stride) {
    const int b = o >> 9, d = o & 511;
    const float* azp = a.AZ + ((size_t)(rp*64 + b))*512;
    const float* abp = a.AB + ((size_t)(rp*64 + b))*512;
    const float4* az4 = (const float4*)azp;
    const float4* ab4 = (const float4*)abp;
    const float4* wir = (const float4*)(a.Wi3 + (size_t)d*512);
    const float4* wiz = (const float4*)(a.Wi3 + (size_t)(512+d)*512);
    const float4* win = (const float4*)(a.Wi3 + (size_t)(1024+d)*512);
    const float4* whr = (const float4*)(a.Wh3 + (size_t)d*512);
    const float4* whz = (const float4*)(a.Wh3 + (size_t)(512+d)*512);
    const float4* whn = (const float4*)(a.Wh3 + (size_t)(1024+d)*512);
    float ir = 0, iz = 0, in_ = 0, hr = 0, hz = 0, hn = 0;
#pragma unroll 4
    for (int k = 0; k < 128; ++k) {
      float4 x = az4[k], h = ab4[k];
      ir += dot4(x, wir[k]); iz += dot4(x, wiz[k]); in_ += dot4(x, win[k]);
      hr += dot4(h, whr[k]); hz += dot4(h, whz[k]); hn += dot4(h, whn[k]);
    }
    float rg = sigm(ir + a.bi3[d] + hr + a.bh3[d]);
    float zg = sigm(iz + a.bi3[512+d] + hz + a.bh3[512+d]);
    float ng = tanhf(in_ + a.bi3[1024+d] + rg*(hn + a.bh3[1024+d]));
    float abv = abp[d];
    float g = (1.f - zg)*ng + zg*abv;
    float rd = a.read[(t<<6) + b];
    a.AB[((size_t)(wp*64 + b))*512 + d] = rd*g + (1.f - rd)*abv;
    int m = (t<<6) + b;
    float zfv = a.zf[(size_t)m*512 + d];
    float qv  = a.cbk[(size_t)a.idx[m]*512 + d];
    float azv = azp[d];
    a.AZ[((size_t)(wp*64 + b))*512 + d] = rd*(zfv + (qv - zfv)) + (1.f - rd)*azv;
  }
}

__device__ __forceinline__ void scan_stageB(const ScanArgs& a, int t, int vt, int stride)
{
  const int pw = (t + 1) & 1;
  for (int o = vt; o < 64*512; o += stride) {
    const int b = o >> 9, n = o & 511;
    const float4* ab4 = (const float4*)(a.AB + ((size_t)(pw*64 + b))*512);
    const float4* az4 = (const float4*)(a.AZ + ((size_t)(pw*64 + b))*512);
    const float4* w = (const float4*)(a.afW + (size_t)n*1024);
    float acc = 0.f;
#pragma unroll 4
    for (int k = 0; k < 128; ++k) acc += dot4(ab4[k], w[k]);
#pragma unroll 4
    for (int k = 0; k < 128; ++k) acc += dot4(az4[k], w[128 + k]);
    a.AF[((size_t)((t&1)*64 + b))*512 + n] = acc + a.afb[n];
  }
}

__device__ __forceinline__ void scan_stageC(const ScanArgs& a, int t, int vt, int stride)
{
  const int rp = t & 1, wp = rp ^ 1;
  for (int o = vt; o < 64*768; o += stride) {
    const int b = o / 768, j = o - b*768;
    const float rd = a.read[(t<<6) + b];
    const float* afp = a.AF + ((size_t)(rp*64 + b))*512;
    const float4* af4 = (const float4*)afp;
    if (j < 512) {
      const int d = j;
      const float4* oz4 = (const float4*)(a.OZ + ((size_t)(rp*64 + b))*256);
      const float* obp = a.OB + ((size_t)(rp*64 + b))*512;
      const float4* ob4 = (const float4*)obp;
      const float4* wir = (const float4*)(a.ubWi + (size_t)d*768);
      const float4* wiz = (const float4*)(a.ubWi + (size_t)(512+d)*768);
      const float4* win = (const float4*)(a.ubWi + (size_t)(1024+d)*768);
      const float4* whr = (const float4*)(a.ubWh + (size_t)d*512);
      const float4* whz = (const float4*)(a.ubWh + (size_t)(512+d)*512);
      const float4* whn = (const float4*)(a.ubWh + (size_t)(1024+d)*512);
      float ir = 0, iz = 0, in_ = 0, hr = 0, hz = 0, hn = 0;
#pragma unroll 4
      for (int k = 0; k < 64; ++k) { float4 x = oz4[k]; ir += dot4(x, wir[k]); iz += dot4(x, wiz[k]); in_ += dot4(x, win[k]); }
#pragma unroll 4
      for (int k = 0; k < 128; ++k) { float4 x = af4[k]; ir += dot4(x, wir[64+k]); iz += dot4(x, wiz[64+k]); in_ += dot4(x, win[64+k]); }
#pragma unroll 4
      for (int k = 0; k < 128; ++k) { float4 h = ob4[k]; hr += dot4(h, whr[k]); hz += dot4(h, whz[k]); hn += dot4(h, whn[k]); }
      float rg = sigm(ir + a.ubbi[d] + hr + a.ubbh[d]);
      float zg = sigm(iz + a.ubbi[512+d] + hz + a.ubbh[512+d]);
      float ng = tanhf(in_ + a.ubbi[1024+d] + rg*(hn + a.ubbh[1024+d]));
      float obv = obp[d];
      float h2 = (1.f - zg)*ng + zg*obv;
      a.OB[((size_t)(wp*64 + b))*512 + d] = rd*afp[d] + (1.f - rd)*h2;
    } else {
      const int jj = j - 512;
      const float4* op4 = (const float4*)(a.opf + ((size_t)((t<<6) + b))*512);
      const float4* wm = (const float4*)(a.pomW + (size_t)jj*1024);
      const float4* wsd = (const float4*)(a.posW + (size_t)jj*1024);
      float am = 0, as_ = 0;
#pragma unroll 4
      for (int k = 0; k < 128; ++k) { float4 x = op4[k]; am += dot4(x, wm[k]); as_ += dot4(x, wsd[k]); }
#pragma unroll 4
      for (int k = 0; k < 128; ++k) { float4 x = af4[k]; am += dot4(x, wm[128+k]); as_ += dot4(x, wsd[128+k]); }
      float mean = am + a.pomb[jj];
      float sv = sigm(as_ + a.posb[jj]);
      float ep = a.eps[((size_t)((b<<7) + t))*256 + jj];
      a.OZ[((size_t)(wp*64 + b))*256 + jj] = mean + sv*ep;
    }
  }
}

__device__ __forceinline__ void scan_stageD(const ScanArgs& a, int t, int vt, int stride)
{
  const int pw = (t + 1) & 1;
  for (int o = vt; o < 64*512; o += stride) {
    const int b = o >> 9, n = o & 511;
    const float4* ob4 = (const float4*)(a.OB + ((size_t)(pw*64 + b))*512);
    const float4* oz4 = (const float4*)(a.OZ + ((size_t)(pw*64 + b))*256);
    const float4* w = (const float4*)(a.ofW + (size_t)n*768);
    float acc = 0.f;
#pragma unroll 4
    for (int k = 0; k < 128; ++k) acc += dot4(ob4[k], w[k]);
#pragma unroll 4
    for (int k = 0; k < 64; ++k)  acc += dot4(oz4[k], w[128 + k]);
    a.ofs[((size_t)((t<<6) + b))*512 + n] = acc + a.ofb[n];
  }
}

// blocks: A=64 B=64 C=96 D=32 (sum 256); 512 threads.
#define SCAN_A 64
#define SCAN_B 64
#define SCAN_C 96
#define SCAN_D 32

__launch_bounds__(512)
__global__ void scan_k(ScanArgs a)
{
  cg::grid_group grid = cg::this_grid();
  const int bid = blockIdx.x, tid = threadIdx.x;
  for (int p = 0; p < 131; ++p) {
    if (bid < SCAN_A) {
      if (p < 128) scan_stageA(a, p, bid*512 + tid, SCAN_A*512);
    } else if (bid < SCAN_A + SCAN_B) {
      int t = p - 1; if (t >= 0 && t < 128) scan_stageB(a, t, (bid-SCAN_A)*512 + tid, SCAN_B*512);
    } else if (bid < SCAN_A + SCAN_B + SCAN_C) {
      int t = p - 2; if (t >= 0 && t < 128) scan_stageC(a, t, (bid-SCAN_A-SCAN_B)*512 + tid, SCAN_C*512);
    } else {
      int t = p - 3; if (t >= 0 && t < 128) scan_stageD(a, t, (bid-SCAN_A-SCAN_B-SCAN_C)*512 + tid, SCAN_D*512);
    }
    __threadfence();
    grid.sync();
  }
}

// ---------- vq loss reduce ----------
__launch_bounds__(256)
__global__ void vqred_k(const float* __restrict__ part, const float* __restrict__ read,
                        float* __restrict__ o)
{
  int tid = threadIdx.x;
  float s = 0.f, c = 0.f;
  for (int i = tid; i < 8192; i += 256) { s += part[i]; c += read[i]; }
  for (int off = 32; off; off >>= 1) { s += __shfl_down(s, off); c += __shfl_down(c, off); }
  __shared__ float ss[4], sc[4];
  int w = tid >> 6;
  if ((tid & 63) == 0) { ss[w] = s; sc[w] = c; }
  __syncthreads();
  if (tid == 0) {
    float st = ss[0] + ss[1] + ss[2] + ss[3];
    float ct = sc[0] + sc[1] + sc[2] + sc[3];
    float cnt = ct * 512.f;
    o[0] = (2.f * st) / fmaxf(cnt, 1.f);
  }
}

// ---------- host launcher ----------
extern "C" void kernel_launch(void* const* d_in, const int* in_sizes, int n_in,
                              void* d_out, int out_size, void* d_ws, size_t ws_size,
                              hipStream_t stream)
{
  (void)in_sizes; (void)n_in; (void)out_size;
  const float* obs      = (const float*)d_in[0];
  const int*   actions  = (const int*)  d_in[1];
  const float* bnd_u    = (const float*)d_in[2];
  const float* vq_u     = (const float*)d_in[3];
  const float* obs_eps  = (const float*)d_in[4];
  const float* enc_W    = (const float*)d_in[5];
  const float* enc_b    = (const float*)d_in[6];
  const float* act_tab  = (const float*)d_in[7];
  const float* comb_W   = (const float*)d_in[8];
  const float* comb_b   = (const float*)d_in[9];
  const float* pb_convW = (const float*)d_in[10];
  const float* pb_gamma = (const float*)d_in[11];
  const float* pb_beta  = (const float*)d_in[12];
  const float* pb_fW    = (const float*)d_in[13];
  const float* pb_fb    = (const float*)d_in[14];
  const float* grus_Wi  = (const float*)d_in[15];
  const float* grus_Wh  = (const float*)d_in[16];
  const float* grus_bi  = (const float*)d_in[17];
  const float* grus_bh  = (const float*)d_in[18];
  const float* ub_Wi    = (const float*)d_in[19];
  const float* ub_Wh    = (const float*)d_in[20];
  const float* ub_bi    = (const float*)d_in[21];
  const float* ub_bh    = (const float*)d_in[22];
  const float* vq_m1W   = (const float*)d_in[23];
  const float* vq_m1b   = (const float*)d_in[24];
  const float* vq_m2W   = (const float*)d_in[25];
  const float* vq_m2b   = (const float*)d_in[26];
  const float* codebook = (const float*)d_in[27];
  const float* po_meanW = (const float*)d_in[28];
  const float* po_meanb = (const float*)d_in[29];
  const float* po_stdW  = (const float*)d_in[30];
  const float* po_stdb  = (const float*)d_in[31];
  const float* af_W     = (const float*)d_in[32];
  const float* af_b     = (const float*)d_in[33];
  const float* of_W     = (const float*)d_in[34];
  const float* of_b     = (const float*)d_in[35];
  const float* dec_W    = (const float*)d_in[36];
  const float* dec_b    = (const float*)d_in[37];
  float* out = (float*)d_out;
  char* ws = (char*)d_ws;

  size_t o_ = 0;
  auto take = [&](size_t n) { size_t r = o_; o_ += (n + 255) & ~(size_t)255; return r; };
  float* W0R  = (float*)(ws + take((size_t)512*2560*4));
  float* W1R  = (float*)(ws + take((size_t)512*2560*4));
  float* WFR  = (float*)(ws + take((size_t)2*2560*4));
  float* CBSQ = (float*)(ws + take(10*4));
  float* FEAT = (float*)(ws + take((size_t)8192*512*4));   // later: zf
  float* CBUF = (float*)(ws + take((size_t)2*8192*512*4)); // convA|convB; later azin; later ofs
  float* EBUF = (float*)(ws + take((size_t)8192*256*4));   // e; later z1
  float* OPF  = (float*)(ws + take((size_t)8192*512*4));
  float* READ = (float*)(ws + take(8192*4));
  int*   IDX  = (int*)  (ws + take(8192*4));
  double* ST  = (double*)(ws + take(1024*8));
  float* MV   = (float*)(ws + take(1024*4));
  float* VQP  = (float*)(ws + take(8192*4));
  size_t hst_off = take((size_t)3*2*64*512*4); float* HST = (float*)(ws + hst_off);
  float* AZ = (float*)(ws + take((size_t)2*64*512*4));
  float* AB = (float*)(ws + take((size_t)2*64*512*4));
  float* OB = (float*)(ws + take((size_t)2*64*512*4));
  float* OZ = (float*)(ws + take((size_t)2*64*256*4));
  size_t af_off = take((size_t)2*64*512*4); float* AF = (float*)(ws + af_off);
  if (ws_size < o_) return; // workspace too small; fail loudly via validation

  float* CBA = CBUF;
  float* CBB = CBUF + (size_t)8192*512;
  float* AZIN = CBUF;
  float* OFS = CBUF;
  float* ZF = FEAT;
  float* Z1 = EBUF;

  // 1. repack conv weights + codebook sumsq
  repack_k<<<10261, 256, 0, stream>>>(pb_convW, pb_fW, codebook, W0R, W1R, WFR, CBSQ);
  // 2. e = obs @ enc_W^T + enc_b
  gemm_k<0><<<dim3(64,2), 256, 0, stream>>>(obs, enc_W, enc_b, EBUF, 8192, 256, 1024, 256, nullptr, nullptr);
  // 3. feat = [act_emb | e] @ comb_W^T + comb_b
  gemm_k<1><<<dim3(64,4), 256, 0, stream>>>(EBUF, comb_W, comb_b, FEAT, 8192, 512, 320, 512, actions, act_tab);
  // 4. conv layer 0
  gemm_k<2><<<dim3(64,4), 256, 0, stream>>>(FEAT, W0R, nullptr, CBA, 8192, 512, 2560, 512, nullptr, nullptr);
  hipMemsetAsync(ST, 0, 1024*8, stream);
  stats_k<<<64, 256, 0, stream>>>(CBA, ST);
  statsfin_k<<<2, 256, 0, stream>>>(ST, MV);
  normelu_k<<<4096, 256, 0, stream>>>(CBA, MV, pb_gamma, pb_beta, CBB);
  // 5. conv layer 1
  gemm_k<2><<<dim3(64,4), 256, 0, stream>>>(CBB, W1R, nullptr, CBA, 8192, 512, 2560, 512, nullptr, nullptr);
  hipMemsetAsync(ST, 0, 1024*8, stream);
  stats_k<<<64, 256, 0, stream>>>(CBA, ST);
  statsfin_k<<<2, 256, 0, stream>>>(ST, MV);
  normelu_k<<<4096, 256, 0, stream>>>(CBA, MV, pb_gamma + 512, pb_beta + 512, CBB);
  // zero recurrent state (HST..OZ contiguous; AF needs no init)
  hipMemsetAsync(ws + hst_off, 0, af_off - hst_off, stream);
  // 6. boundary read bits
  fconv_k<<<8192, 64, 0, stream>>>(CBB, WFR, pb_fb, bnd_u, READ);
  // 7. three GRU sweeps (cooperative)
  SweepArgs sa{FEAT, READ, grus_Wi, grus_Wh, grus_bi, grus_bh, AZIN, OPF, HST};
  void* sargs[] = {&sa};
  hipLaunchCooperativeKernel(sweep_k, dim3(256), dim3(768), sargs, 0, stream);
  // 8. VQ MLP
  gemm_k<3><<<dim3(64,1), 256, 0, stream>>>(AZIN, vq_m1W, vq_m1b, Z1, 8192, 128, 1024, 128, nullptr, nullptr);
  gemm_k<0><<<dim3(64,4), 256, 0, stream>>>(Z1, vq_m2W, vq_m2b, ZF, 8192, 512, 128, 512, nullptr, nullptr);
  // 9. VQ select + partial loss
  dist_k<<<8192, 64, 0, stream>>>(ZF, codebook, CBSQ, vq_u, READ, IDX, VQP);
  // 10. main scan (cooperative, pipelined)
  ScanArgs sc{ZF, codebook, IDX, READ, OPF, obs_eps,
              grus_Wi + (size_t)3*1536*512, grus_Wh + (size_t)3*1536*512,
              grus_bi + 3*1536, grus_bh + 3*1536,
              ub_Wi, ub_Wh, ub_bi, ub_bh,
              po_meanW, po_meanb, po_stdW, po_stdb,
              af_W, af_b, of_W, of_b,
              AZ, AB, OB, OZ, AF, OFS};
  void* scargs[] = {&sc};
  hipLaunchCooperativeKernel(scan_k, dim3(256), dim3(512), scargs, 0, stream);
  // 11. decoder
  gemm_k<4><<<dim3(64,8), 256, 0, stream>>>(OFS, dec_W, dec_b, out, 8192, 1024, 512, 1024, nullptr, nullptr);
  // 12. vq loss
  vqred_k<<<1, 256, 0, stream>>>(VQP, READ, out + 8388608);
}

// Round 7
// 36538.147 us; speedup vs baseline: 2.2859x; 2.2859x over previous
//
#include <hip/hip_runtime.h>
#include <hip/hip_cooperative_groups.h>
#include <math.h>

namespace cg = cooperative_groups;

// ---------- helpers ----------
__device__ __forceinline__ float4 ld4(const float* p) { return *reinterpret_cast<const float4*>(p); }
__device__ __forceinline__ float dot4(float4 a, float4 b) { return a.x*b.x + a.y*b.y + a.z*b.z + a.w*b.w; }
__device__ __forceinline__ float sigm(float x) { return 1.f/(1.f+expf(-x)); }
__device__ __forceinline__ float gumb(float u) {
  u = fminf(fmaxf(u, 1e-6f), 1.f - 1e-6f);
  return -logf(-logf(u));
}

// ---------- repack conv weights: [o][i][k] -> [o][k*512+i]; pb_fW too; codebook row sumsq ----------
__launch_bounds__(256)
__global__ void repack_k(const float* __restrict__ convW, const float* __restrict__ fW,
                         const float* __restrict__ cbk,
                         float* __restrict__ W0R, float* __restrict__ W1R,
                         float* __restrict__ WFR, float* __restrict__ CBSQ)
{
  long i = (long)blockIdx.x*256 + threadIdx.x;
  const long NC = 2L*512*2560;
  if (i < NC) {
    int l = (int)(i / (512*2560)); int rem = (int)(i % (512*2560));
    int n = rem / 2560; int r2 = rem - n*2560; int k = r2 >> 9; int ii = r2 & 511;
    float v = convW[(((size_t)(l*512 + n)*512 + ii)*5) + k];
    (l ? W1R : W0R)[(size_t)n*2560 + r2] = v;
  } else if (i < NC + 2*2560) {
    long j = i - NC; int o = (int)(j / 2560); int r2 = (int)(j - o*2560);
    int k = r2 >> 9; int ii = r2 & 511;
    WFR[(size_t)o*2560 + r2] = fW[((size_t)o*512 + ii)*5 + k];
  } else if (i < NC + 2*2560 + 10) {
    int j = (int)(i - (NC + 2*2560));
    float s = 0.f;
    for (int d = 0; d < 512; ++d) { float c = cbk[j*512 + d]; s += c*c; }
    CBSQ[j] = s;
  }
}

// ---------- tiled f32 GEMM: C[M,N] = A[M,K] @ Bw[N,K]^T (+bias) ----------
// MODE 0 plain, 1 comb-gather, 2 conv-im2col, 3 relu, 4 dec-row-remap
template<int MODE>
__launch_bounds__(256)
__global__ void gemm_k(const float* __restrict__ A, const float* __restrict__ Bw,
                       const float* __restrict__ bias, float* __restrict__ C,
                       int M, int N, int K, int ldc,
                       const int* __restrict__ aux_i, const float* __restrict__ aux_f)
{
  __shared__ float As[16][132];
  __shared__ float Bs[16][132];
  const int tid = threadIdx.x;
  const int ty = tid >> 4, tx = tid & 15;
  const int m0 = blockIdx.x * 128, n0 = blockIdx.y * 128;
  float acc[8][8];
#pragma unroll
  for (int i = 0; i < 8; ++i)
#pragma unroll
    for (int j = 0; j < 8; ++j) acc[i][j] = 0.f;

  for (int k0 = 0; k0 < K; k0 += 16) {
#pragma unroll
    for (int jj = 0; jj < 2; ++jj) {
      int li = tid + jj*256;
      int row = li >> 2;
      int kc = (li & 3) << 2;
      int gm = m0 + row, gk = k0 + kc;
      float4 av;
      if constexpr (MODE == 2) {
        int b = gm >> 7, s = gm & 127;
        int kk = gk >> 9, ii = gk & 511;
        int sr = s + kk - 4;
        if (sr >= 0) av = ld4(A + (((size_t)((b<<7)+sr))<<9) + ii);
        else av = make_float4(0.f,0.f,0.f,0.f);
      } else if constexpr (MODE == 1) {
        if (gk < 64) av = ld4(aux_f + (size_t)aux_i[gm]*64 + gk);
        else av = ld4(A + (size_t)gm*256 + (gk - 64));
      } else {
        av = ld4(A + (size_t)gm*K + gk);
      }
      As[kc+0][row] = av.x; As[kc+1][row] = av.y; As[kc+2][row] = av.z; As[kc+3][row] = av.w;
      float4 bv = ld4(Bw + (size_t)(n0+row)*K + gk);
      Bs[kc+0][row] = bv.x; Bs[kc+1][row] = bv.y; Bs[kc+2][row] = bv.z; Bs[kc+3][row] = bv.w;
    }
    __syncthreads();
#pragma unroll
    for (int kk = 0; kk < 16; ++kk) {
      float a[8], b[8];
      *(float4*)&a[0] = *(const float4*)&As[kk][ty*4];
      *(float4*)&a[4] = *(const float4*)&As[kk][ty*4 + 64];
      *(float4*)&b[0] = *(const float4*)&Bs[kk][tx*4];
      *(float4*)&b[4] = *(const float4*)&Bs[kk][tx*4 + 64];
#pragma unroll
      for (int i = 0; i < 8; ++i)
#pragma unroll
        for (int j = 0; j < 8; ++j) acc[i][j] += a[i]*b[j];
    }
    __syncthreads();
  }
#pragma unroll
  for (int i = 0; i < 8; ++i) {
    int m = m0 + ty*4 + (i & 3) + ((i >> 2) << 6);
    int crow = m;
    if constexpr (MODE == 4) crow = ((m & 63) << 7) + (m >> 6);
#pragma unroll
    for (int jh = 0; jh < 2; ++jh) {
      int n = n0 + tx*4 + jh*64;
      float4 v;
      float* vp = &v.x;
#pragma unroll
      for (int q = 0; q < 4; ++q) {
        float t = acc[i][jh*4 + q];
        if (bias) t += bias[n + q];
        if constexpr (MODE == 3) t = fmaxf(t, 0.f);
        vp[q] = t;
      }
      *(float4*)(C + (size_t)crow*ldc + n) = v;
    }
  }
}

// ---------- per-channel stats over (b,s) ----------
__launch_bounds__(256)
__global__ void stats_k(const float* __restrict__ y, double* __restrict__ st)
{
  const int blk = blockIdx.x;   // 64 blocks x 128 rows
  const int o = threadIdx.x;    // channel o and o+256
  double s0 = 0, q0 = 0, s1 = 0, q1 = 0;
  for (int r = 0; r < 128; ++r) {
    const float* row = y + ((size_t)(blk*128 + r))*512;
    float v0 = row[o], v1 = row[o + 256];
    s0 += v0; q0 += (double)v0*(double)v0;
    s1 += v1; q1 += (double)v1*(double)v1;
  }
  atomicAdd(&st[o], s0);        atomicAdd(&st[512 + o], q0);
  atomicAdd(&st[o + 256], s1);  atomicAdd(&st[512 + o + 256], q1);
}

__launch_bounds__(256)
__global__ void statsfin_k(const double* __restrict__ st, float* __restrict__ mv)
{
  int o = blockIdx.x*256 + threadIdx.x;
  if (o >= 512) return;
  double mean = st[o] / 8192.0;
  double var = st[512 + o] / 8192.0 - mean*mean;
  mv[o] = (float)mean;
  mv[512 + o] = (float)(1.0 / sqrt(var + 1e-5));
}

__launch_bounds__(256)
__global__ void normelu_k(const float* __restrict__ y, const float* __restrict__ mv,
                          const float* __restrict__ gamma, const float* __restrict__ beta,
                          float* __restrict__ x)
{
  int e4 = blockIdx.x*256 + threadIdx.x;
  if (e4 >= 8192*128) return;
  int o = (e4 & 127) << 2;
  float4 v = ld4(y + (size_t)e4*4);
  float* vp = &v.x;
  float r[4];
#pragma unroll
  for (int q = 0; q < 4; ++q) {
    float t = (vp[q] - mv[o+q]) * mv[512+o+q] * gamma[o+q] + beta[o+q];
    r[q] = t > 0.f ? t : expm1f(t);
  }
  *(float4*)(x + (size_t)e4*4) = make_float4(r[0], r[1], r[2], r[3]);
}

// ---------- final conv (D->2) + gumbel hard argmax -> read bit ----------
__launch_bounds__(64)
__global__ void fconv_k(const float* __restrict__ x, const float* __restrict__ WFR,
                        const float* __restrict__ fb, const float* __restrict__ bnd_u,
                        float* __restrict__ read)
{
  const int m = blockIdx.x;      // (b,s)
  const int l = threadIdx.x;
  const int b = m >> 7, s = m & 127;
  float a0 = 0.f, a1 = 0.f;
  for (int k = 0; k < 5; ++k) {
    int sr = s + k - 4;
    if (sr < 0) continue;
    const float* xr = x + ((size_t)((b<<7)+sr))*512;
    const float* w0 = WFR + k*512;
    const float* w1 = WFR + 2560 + k*512;
#pragma unroll
    for (int it = 0; it < 8; ++it) { float xv = xr[it*64 + l]; a0 += xv*w0[it*64 + l]; a1 += xv*w1[it*64 + l]; }
  }
  for (int off = 32; off; off >>= 1) { a0 += __shfl_down(a0, off); a1 += __shfl_down(a1, off); }
  if (l == 0) {
    a0 += fb[0]; a1 += fb[1];
    float g0 = gumb(bnd_u[(size_t)m*2 + 0]);
    float g1 = gumb(bnd_u[(size_t)m*2 + 1]);
    read[(s<<6) + b] = (a0 + g0 >= a1 + g1) ? 1.f : 0.f;  // argmax==0 -> read=1
  }
}

// ---------- transposes: FEATT[s][k][b], EPST[t][jj][b] ----------
__launch_bounds__(256)
__global__ void trans1_k(const float* __restrict__ feat, const float* __restrict__ eps,
                         float* __restrict__ featT, float* __restrict__ epsT)
{
  int i = blockIdx.x*256 + threadIdx.x;
  if (i < 4194304) {
    int b = i & 63; int k = (i >> 6) & 511; int s = i >> 15;
    featT[i] = feat[((size_t)((b<<7)+s))*512 + k];
  } else {
    int j = i - 4194304;
    int b = j & 63; int jj = (j >> 6) & 255; int t = j >> 14;
    epsT[j] = eps[((size_t)((b<<7)+t))*256 + jj];
  }
}

// ---------- TQZ[t][d][b] = zf + (q - zf) ----------
__launch_bounds__(256)
__global__ void trans2_k(const float* __restrict__ zf, const float* __restrict__ cbk,
                         const int* __restrict__ idx, float* __restrict__ tqz)
{
  int i = blockIdx.x*256 + threadIdx.x;
  int b = i & 63; int d = (i >> 6) & 511; int t = i >> 15;
  int m = (t<<6) + b;
  float zv = zf[(size_t)m*512 + d];
  float qv = cbk[(size_t)idx[m]*512 + d];
  tqz[i] = zv + (qv - zv);
}

// ---------- cooperative sweep: lanes=batch, wave=(sweep,d), uniform weights ----------
struct SweepArgs {
  const float* featT; const float* read;
  const float* Wi; const float* Wh; const float* bi; const float* bh;
  float* azin; float* opft; float* hst;   // hst: [3][2][512][64]
};

__launch_bounds__(512)
__global__ void sweep_k(SweepArgs a)
{
  cg::grid_group grid = cg::this_grid();
  const int wid = __builtin_amdgcn_readfirstlane(threadIdx.x >> 6);
  const int lane = threadIdx.x & 63;
  const int pair = blockIdx.x*8 + wid;   // 0..1535
  const int sweep = pair >> 9;           // 0..2
  const int d = pair & 511;
  const float* wi = a.Wi + ((size_t)sweep*1536 + d)*512;
  const float* wh = a.Wh + ((size_t)sweep*1536 + d)*512;
  const float bir = a.bi[sweep*1536 + d], biz = a.bi[sweep*1536 + 512 + d], bin = a.bi[sweep*1536 + 1024 + d];
  const float bhr = a.bh[sweep*1536 + d], bhz = a.bh[sweep*1536 + 512 + d], bhn = a.bh[sweep*1536 + 1024 + d];
  float* ht = a.hst + (size_t)sweep*2*32768;
  for (int t = 0; t < 128; ++t) {
    const int src = (sweep == 1) ? (127 - t) : t;
    const float* ft = a.featT + (size_t)src*32768;
    const int rp = t & 1, wp = rp ^ 1;
    const float* h = ht + rp*32768;
    float ir = 0.f, iz = 0.f, in_ = 0.f, hr = 0.f, hz = 0.f, hn = 0.f;
#pragma unroll 8
    for (int k = 0; k < 512; ++k) {
      float f = ft[(k<<6) + lane];
      float hv = h[(k<<6) + lane];
      ir = fmaf(wi[k], f, ir); iz = fmaf(wi[262144 + k], f, iz); in_ = fmaf(wi[524288 + k], f, in_);
      hr = fmaf(wh[k], hv, hr); hz = fmaf(wh[262144 + k], hv, hz); hn = fmaf(wh[524288 + k], hv, hn);
    }
    float rg = sigm(ir + bir + hr + bhr);
    float zg = sigm(iz + biz + hz + bhz);
    float ng = tanhf(in_ + bin + rg*(hn + bhn));
    float hp = h[(d<<6) + lane];
    float hnew = (1.f - zg)*ng + zg*hp;
    float rd = a.read[(src<<6) + lane];
    if (sweep == 0)      a.azin[((size_t)((src<<6)+lane))*1024 + d] = hnew;
    else if (sweep == 1) a.azin[((size_t)((src<<6)+lane))*1024 + 512 + d] = hnew;
    else                 a.opft[((size_t)src*512 + d)*64 + lane] = hnew;
    ht[wp*32768 + (d<<6) + lane] = hnew*(1.f - rd);
    __threadfence();
    grid.sync();
  }
}

// ---------- VQ distance / idx / partial loss ----------
__launch_bounds__(64)
__global__ void dist_k(const float* __restrict__ zf, const float* __restrict__ cbk,
                       const float* __restrict__ cbsq, const float* __restrict__ vq_u,
                       const float* __restrict__ read, int* __restrict__ idx,
                       float* __restrict__ part)
{
  const int m = blockIdx.x;     // (s,b)
  const int l = threadIdx.x;
  const float* z = zf + (size_t)m*512;
  float acc[10];
#pragma unroll
  for (int j = 0; j < 10; ++j) acc[j] = 0.f;
  float sq = 0.f;
  for (int it = 0; it < 8; ++it) {
    float zv = z[it*64 + l];
    sq += zv*zv;
#pragma unroll
    for (int j = 0; j < 10; ++j) acc[j] += zv * cbk[j*512 + it*64 + l];
  }
  for (int off = 32; off; off >>= 1) {
    sq += __shfl_down(sq, off);
#pragma unroll
    for (int j = 0; j < 10; ++j) acc[j] += __shfl_down(acc[j], off);
  }
  int bj = 0;
  if (l == 0) {
    const int s = m >> 6, b = m & 63;
    float sd[10]; float mx = -1e30f;
#pragma unroll
    for (int j = 0; j < 10; ++j) { float dist = sq + cbsq[j] - 2.f*acc[j]; sd[j] = -dist/0.1f; mx = fmaxf(mx, sd[j]); }
    float best = -1e30f;
#pragma unroll
    for (int j = 0; j < 10; ++j) {
      float v = fminf(fmaxf(sd[j] - mx, -1000.f), 10.f);
      v += gumb(vq_u[((size_t)((b<<7)+s))*10 + j]);
      if (v > best) { best = v; bj = j; }
    }
    idx[m] = bj;
  }
  bj = __shfl(bj, 0);
  float e2 = 0.f;
  for (int it = 0; it < 8; ++it) { float dv = cbk[bj*512 + it*64 + l] - z[it*64 + l]; e2 += dv*dv; }
  for (int off = 32; off; off >>= 1) e2 += __shfl_down(e2, off);
  if (l == 0) part[m] = read[m]*e2;
}

// ---------- cooperative main scan: lanes=batch, wave=task, transposed state ----------
// State: AZT/ABT/OBT/AFT [2][512][64], OZT [2][256][64]
struct ScanArgs {
  const float* tqz; const float* read; const float* opft; const float* epst;
  const float* Wi3; const float* Wh3; const float* bi3; const float* bh3;
  const float* ubWi; const float* ubWh; const float* ubbi; const float* ubbh;
  const float* pomW; const float* pomb; const float* posW; const float* posb;
  const float* afW; const float* afb; const float* ofW; const float* ofb;
  float* AZT; float* ABT; float* OBT; float* OZT; float* AFT; float* ofs;
};

__device__ __forceinline__ void sA(const ScanArgs& a, int t, int d, int lane)
{
  const int rp = t & 1, wp = rp ^ 1;
  const float* azt = a.AZT + rp*32768;
  const float* abt = a.ABT + rp*32768;
  const float* wi = a.Wi3 + (size_t)d*512;
  const float* wh = a.Wh3 + (size_t)d*512;
  float ir = 0, iz = 0, in_ = 0, hr = 0, hz = 0, hn = 0;
#pragma unroll 8
  for (int k = 0; k < 512; ++k) {
    float xz = azt[(k<<6) + lane];
    float xb = abt[(k<<6) + lane];
    ir = fmaf(wi[k], xz, ir); iz = fmaf(wi[262144 + k], xz, iz); in_ = fmaf(wi[524288 + k], xz, in_);
    hr = fmaf(wh[k], xb, hr); hz = fmaf(wh[262144 + k], xb, hz); hn = fmaf(wh[524288 + k], xb, hn);
  }
  float rg = sigm(ir + a.bi3[d] + hr + a.bh3[d]);
  float zg = sigm(iz + a.bi3[512 + d] + hz + a.bh3[512 + d]);
  float ng = tanhf(in_ + a.bi3[1024 + d] + rg*(hn + a.bh3[1024 + d]));
  float abv = abt[(d<<6) + lane];
  float azv = azt[(d<<6) + lane];
  float rd = a.read[(t<<6) + lane];
  float g = (1.f - zg)*ng + zg*abv;
  a.ABT[wp*32768 + (d<<6) + lane] = rd*g + (1.f - rd)*abv;
  float tq = a.tqz[(size_t)t*32768 + (d<<6) + lane];
  a.AZT[wp*32768 + (d<<6) + lane] = rd*tq + (1.f - rd)*azv;
}

__device__ __forceinline__ void sB(const ScanArgs& a, int t, int n, int lane)
{
  const int pw = (t + 1) & 1;
  const float* abt = a.ABT + pw*32768;
  const float* azt = a.AZT + pw*32768;
  const float* w = a.afW + (size_t)n*1024;
  float acc = 0.f;
#pragma unroll 8
  for (int k = 0; k < 512; ++k) {
    acc = fmaf(w[k], abt[(k<<6) + lane], acc);
    acc = fmaf(w[512 + k], azt[(k<<6) + lane], acc);
  }
  a.AFT[(t & 1)*32768 + (n<<6) + lane] = acc + a.afb[n];
}

__device__ __forceinline__ void sCg(const ScanArgs& a, int t, int d, int lane)
{
  const int rp = t & 1, wp = rp ^ 1;
  const float* ozt = a.OZT + rp*16384;
  const float* aft = a.AFT + rp*32768;
  const float* obt = a.OBT + rp*32768;
  const float* wi = a.ubWi + (size_t)d*768;
  const float* wh = a.ubWh + (size_t)d*512;
  float ir = 0, iz = 0, in_ = 0;
#pragma unroll 8
  for (int k = 0; k < 256; ++k) {
    float x = ozt[(k<<6) + lane];
    ir = fmaf(wi[k], x, ir); iz = fmaf(wi[393216 + k], x, iz); in_ = fmaf(wi[786432 + k], x, in_);
  }
#pragma unroll 8
  for (int k = 0; k < 512; ++k) {
    float x = aft[(k<<6) + lane];
    ir = fmaf(wi[256 + k], x, ir); iz = fmaf(wi[393216 + 256 + k], x, iz); in_ = fmaf(wi[786432 + 256 + k], x, in_);
  }
  float hr = 0, hz = 0, hn = 0;
#pragma unroll 8
  for (int k = 0; k < 512; ++k) {
    float h = obt[(k<<6) + lane];
    hr = fmaf(wh[k], h, hr); hz = fmaf(wh[262144 + k], h, hz); hn = fmaf(wh[524288 + k], h, hn);
  }
  float rg = sigm(ir + a.ubbi[d] + hr + a.ubbh[d]);
  float zg = sigm(iz + a.ubbi[512 + d] + hz + a.ubbh[512 + d]);
  float ng = tanhf(in_ + a.ubbi[1024 + d] + rg*(hn + a.ubbh[1024 + d]));
  float obv = obt[(d<<6) + lane];
  float h2 = (1.f - zg)*ng + zg*obv;
  float rd = a.read[(t<<6) + lane];
  float afv = aft[(d<<6) + lane];
  a.OBT[wp*32768 + (d<<6) + lane] = rd*afv + (1.f - rd)*h2;
}

__device__ __forceinline__ void sCp(const ScanArgs& a, int t, int jj, int lane)
{
  const int rp = t & 1, wp = rp ^ 1;
  const float* opft = a.opft + (size_t)t*32768;
  const float* aft = a.AFT + rp*32768;
  const float* wm = a.pomW + (size_t)jj*1024;
  const float* ws = a.posW + (size_t)jj*1024;
  float am = 0, as_ = 0;
#pragma unroll 8
  for (int k = 0; k < 512; ++k) {
    float x = opft[(k<<6) + lane];
    am = fmaf(wm[k], x, am); as_ = fmaf(ws[k], x, as_);
  }
#pragma unroll 8
  for (int k = 0; k < 512; ++k) {
    float x = aft[(k<<6) + lane];
    am = fmaf(wm[512 + k], x, am); as_ = fmaf(ws[512 + k], x, as_);
  }
  float mean = am + a.pomb[jj];
  float sv = sigm(as_ + a.posb[jj]);
  float ep = a.epst[(size_t)t*16384 + (jj<<6) + lane];
  a.OZT[wp*16384 + (jj<<6) + lane] = mean + sv*ep;
}

__device__ __forceinline__ void sD(const ScanArgs& a, int t, int n0, int lane)
{
  const int pw = (t + 1) & 1;
  const float* obt = a.OBT + pw*32768;
  const float* ozt = a.OZT + pw*16384;
  const float* w0 = a.ofW + (size_t)n0*768;
  const float* w1 = w0 + 768;
  float a0 = 0, a1 = 0;
#pragma unroll 8
  for (int k = 0; k < 512; ++k) {
    float x = obt[(k<<6) + lane];
    a0 = fmaf(w0[k], x, a0); a1 = fmaf(w1[k], x, a1);
  }
#pragma unroll 8
  for (int k = 0; k < 256; ++k) {
    float x = ozt[(k<<6) + lane];
    a0 = fmaf(w0[512 + k], x, a0); a1 = fmaf(w1[512 + k], x, a1);
  }
  float* orow = a.ofs + ((size_t)((t<<6) + lane))*512;
  orow[n0] = a0 + a.ofb[n0];
  orow[n0 + 1] = a1 + a.ofb[n0 + 1];
}

// 256 blocks x 512 threads. Per block waves: 0,1=C-GRU  2,3=A  4,5=B  6=C-po  7=D
// SIMD pairing (wid, wid+4): (CG+B), (CG+B), (A+Cpo), (A+D) -> balanced.
__launch_bounds__(512)
__global__ void scan_k(ScanArgs a)
{
  cg::grid_group grid = cg::this_grid();
  const int bid = blockIdx.x;
  const int wid = __builtin_amdgcn_readfirstlane(threadIdx.x >> 6);
  const int lane = threadIdx.x & 63;
  for (int p = 0; p < 131; ++p) {
    if (wid < 2) {
      int t = p - 2; if (t >= 0 && t < 128) sCg(a, t, bid*2 + wid, lane);
    } else if (wid < 4) {
      if (p < 128) sA(a, p, bid*2 + (wid - 2), lane);
    } else if (wid < 6) {
      int t = p - 1; if (t >= 0 && t < 128) sB(a, t, bid*2 + (wid - 4), lane);
    } else if (wid == 6) {
      int t = p - 2; if (t >= 0 && t < 128) sCp(a, t, bid, lane);
    } else {
      int t = p - 3; if (t >= 0 && t < 128) sD(a, t, bid*2, lane);
    }
    __threadfence();
    grid.sync();
  }
}

// ---------- vq loss reduce ----------
__launch_bounds__(256)
__global__ void vqred_k(const float* __restrict__ part, const float* __restrict__ read,
                        float* __restrict__ o)
{
  int tid = threadIdx.x;
  float s = 0.f, c = 0.f;
  for (int i = tid; i < 8192; i += 256) { s += part[i]; c += read[i]; }
  for (int off = 32; off; off >>= 1) { s += __shfl_down(s, off); c += __shfl_down(c, off); }
  __shared__ float ss[4], sc[4];
  int w = tid >> 6;
  if ((tid & 63) == 0) { ss[w] = s; sc[w] = c; }
  __syncthreads();
  if (tid == 0) {
    float st = ss[0] + ss[1] + ss[2] + ss[3];
    float ct = sc[0] + sc[1] + sc[2] + sc[3];
    float cnt = ct * 512.f;
    o[0] = (2.f * st) / fmaxf(cnt, 1.f);
  }
}

// ---------- host launcher ----------
extern "C" void kernel_launch(void* const* d_in, const int* in_sizes, int n_in,
                              void* d_out, int out_size, void* d_ws, size_t ws_size,
                              hipStream_t stream)
{
  (void)in_sizes; (void)n_in; (void)out_size;
  const float* obs      = (const float*)d_in[0];
  const int*   actions  = (const int*)  d_in[1];
  const float* bnd_u    = (const float*)d_in[2];
  const float* vq_u     = (const float*)d_in[3];
  const float* obs_eps  = (const float*)d_in[4];
  const float* enc_W    = (const float*)d_in[5];
  const float* enc_b    = (const float*)d_in[6];
  const float* act_tab  = (const float*)d_in[7];
  const float* comb_W   = (const float*)d_in[8];
  const float* comb_b   = (const float*)d_in[9];
  const float* pb_convW = (const float*)d_in[10];
  const float* pb_gamma = (const float*)d_in[11];
  const float* pb_beta  = (const float*)d_in[12];
  const float* pb_fW    = (const float*)d_in[13];
  const float* pb_fb    = (const float*)d_in[14];
  const float* grus_Wi  = (const float*)d_in[15];
  const float* grus_Wh  = (const float*)d_in[16];
  const float* grus_bi  = (const float*)d_in[17];
  const float* grus_bh  = (const float*)d_in[18];
  const float* ub_Wi    = (const float*)d_in[19];
  const float* ub_Wh    = (const float*)d_in[20];
  const float* ub_bi    = (const float*)d_in[21];
  const float* ub_bh    = (const float*)d_in[22];
  const float* vq_m1W   = (const float*)d_in[23];
  const float* vq_m1b   = (const float*)d_in[24];
  const float* vq_m2W   = (const float*)d_in[25];
  const float* vq_m2b   = (const float*)d_in[26];
  const float* codebook = (const float*)d_in[27];
  const float* po_meanW = (const float*)d_in[28];
  const float* po_meanb = (const float*)d_in[29];
  const float* po_stdW  = (const float*)d_in[30];
  const float* po_stdb  = (const float*)d_in[31];
  const float* af_W     = (const float*)d_in[32];
  const float* af_b     = (const float*)d_in[33];
  const float* of_W     = (const float*)d_in[34];
  const float* of_b     = (const float*)d_in[35];
  const float* dec_W    = (const float*)d_in[36];
  const float* dec_b    = (const float*)d_in[37];
  float* out = (float*)d_out;
  char* ws = (char*)d_ws;

  size_t o_ = 0;
  auto take = [&](size_t n) { size_t r = o_; o_ += (n + 255) & ~(size_t)255; return r; };
  float* W0R  = (float*)(ws + take((size_t)512*2560*4));
  float* W1R  = (float*)(ws + take((size_t)512*2560*4));
  float* WFR  = (float*)(ws + take((size_t)2*2560*4));
  float* CBSQ = (float*)(ws + take(10*4));
  float* FEAT = (float*)(ws + take((size_t)8192*512*4));   // later: zf
  float* CBUF = (float*)(ws + take((size_t)2*8192*512*4)); // convA|convB; later azin; later ofs
  float* EBUF = (float*)(ws + take((size_t)8192*256*4));   // e; later z1
  float* OPFT = (float*)(ws + take((size_t)8192*512*4));   // [128][512][64]
  float* FEATT= (float*)(ws + take((size_t)8192*512*4));   // [128][512][64]; later TQZ
  float* EPST = (float*)(ws + take((size_t)8192*256*4));   // [128][256][64]
  float* READ = (float*)(ws + take(8192*4));
  int*   IDX  = (int*)  (ws + take(8192*4));
  double* ST  = (double*)(ws + take(1024*8));
  float* MV   = (float*)(ws + take(1024*4));
  float* VQP  = (float*)(ws + take(8192*4));
  size_t st_off = take((size_t)(3*2*32768 + 4*2*32768 + 2*16384)*4);
  float* HST = (float*)(ws + st_off);
  float* AZT = HST + 3*2*32768;
  float* ABT = AZT + 2*32768;
  float* OBT = ABT + 2*32768;
  float* AFT = OBT + 2*32768;
  float* OZT = AFT + 2*32768;
  size_t st_end = o_;
  if (ws_size < o_) return;

  float* CBA = CBUF;
  float* CBB = CBUF + (size_t)8192*512;
  float* AZIN = CBUF;
  float* OFS = CBUF;
  float* ZF = FEAT;
  float* Z1 = EBUF;
  float* TQZ = FEATT;

  // 1. repack conv weights + codebook sumsq
  repack_k<<<10261, 256, 0, stream>>>(pb_convW, pb_fW, codebook, W0R, W1R, WFR, CBSQ);
  // 2. e = obs @ enc_W^T + enc_b
  gemm_k<0><<<dim3(64,2), 256, 0, stream>>>(obs, enc_W, enc_b, EBUF, 8192, 256, 1024, 256, nullptr, nullptr);
  // 3. feat = [act_emb | e] @ comb_W^T + comb_b
  gemm_k<1><<<dim3(64,4), 256, 0, stream>>>(EBUF, comb_W, comb_b, FEAT, 8192, 512, 320, 512, actions, act_tab);
  // 3b. transposes for sweep/scan
  trans1_k<<<24576, 256, 0, stream>>>(FEAT, obs_eps, FEATT, EPST);
  // 4. conv layer 0
  gemm_k<2><<<dim3(64,4), 256, 0, stream>>>(FEAT, W0R, nullptr, CBA, 8192, 512, 2560, 512, nullptr, nullptr);
  hipMemsetAsync(ST, 0, 1024*8, stream);
  stats_k<<<64, 256, 0, stream>>>(CBA, ST);
  statsfin_k<<<2, 256, 0, stream>>>(ST, MV);
  normelu_k<<<4096, 256, 0, stream>>>(CBA, MV, pb_gamma, pb_beta, CBB);
  // 5. conv layer 1
  gemm_k<2><<<dim3(64,4), 256, 0, stream>>>(CBB, W1R, nullptr, CBA, 8192, 512, 2560, 512, nullptr, nullptr);
  hipMemsetAsync(ST, 0, 1024*8, stream);
  stats_k<<<64, 256, 0, stream>>>(CBA, ST);
  statsfin_k<<<2, 256, 0, stream>>>(ST, MV);
  normelu_k<<<4096, 256, 0, stream>>>(CBA, MV, pb_gamma + 512, pb_beta + 512, CBB);
  // zero recurrent state
  hipMemsetAsync(ws + st_off, 0, st_end - st_off, stream);
  // 6. boundary read bits
  fconv_k<<<8192, 64, 0, stream>>>(CBB, WFR, pb_fb, bnd_u, READ);
  // 7. three GRU sweeps (cooperative, wave-per-(sweep,d))
  SweepArgs sa{FEATT, READ, grus_Wi, grus_Wh, grus_bi, grus_bh, AZIN, OPFT, HST};
  void* sargs[] = {&sa};
  hipLaunchCooperativeKernel(sweep_k, dim3(192), dim3(512), sargs, 0, stream);
  // 8. VQ MLP
  gemm_k<3><<<dim3(64,1), 256, 0, stream>>>(AZIN, vq_m1W, vq_m1b, Z1, 8192, 128, 1024, 128, nullptr, nullptr);
  gemm_k<0><<<dim3(64,4), 256, 0, stream>>>(Z1, vq_m2W, vq_m2b, ZF, 8192, 512, 128, 512, nullptr, nullptr);
  // 9. VQ select + partial loss
  dist_k<<<8192, 64, 0, stream>>>(ZF, codebook, CBSQ, vq_u, READ, IDX, VQP);
  // 9b. TQZ transpose (zf + (q - zf)) -> [t][d][b]
  trans2_k<<<16384, 256, 0, stream>>>(ZF, codebook, IDX, TQZ);
  // 10. main scan (cooperative, wave-task pipelined)
  ScanArgs sc{TQZ, READ, OPFT, EPST,
              grus_Wi + (size_t)3*1536*512, grus_Wh + (size_t)3*1536*512,
              grus_bi + 3*1536, grus_bh + 3*1536,
              ub_Wi, ub_Wh, ub_bi, ub_bh,
              po_meanW, po_meanb, po_stdW, po_stdb,
              af_W, af_b, of_W, of_b,
              AZT, ABT, OBT, OZT, AFT, OFS};
  void* scargs[] = {&sc};
  hipLaunchCooperativeKernel(scan_k, dim3(256), dim3(512), scargs, 0, stream);
  // 11. decoder
  gemm_k<4><<<dim3(64,8), 256, 0, stream>>>(OFS, dec_W, dec_b, out, 8192, 1024, 512, 1024, nullptr, nullptr);
  // 12. vq loss
  vqred_k<<<1, 256, 0, stream>>>(VQP, READ, out + 8388608);
}